// Round 12
// baseline (329.003 us; speedup 1.0000x reference)
//
#include <hip/hip_runtime.h>
#include <math.h>

#define SEQ 4096
#define HD  16
#define EMB 64
#define FM  12.0f     // fixed softmax max (log2-domain)

typedef _Float16 half4  __attribute__((ext_vector_type(4)));
typedef __fp16   pk2    __attribute__((ext_vector_type(2)));   // cvt_pkrtz result type
typedef _Float16 h8     __attribute__((ext_vector_type(8)));
typedef float    f32x4  __attribute__((ext_vector_type(4)));

// ---- ws byte layout ----
#define QH_OFF  ((size_t)0)            // f16 [16][4096][16]
#define KH_OFF  ((size_t)(2u<<20))     // f16 [16][4096][16]
#define VT_OFF  ((size_t)(4u<<20))     // f16 [16][16][4096]
#define ATT_OFF ((size_t)(8u<<20))     // f32 [4][4096][64]
#define SCR_OFF ((size_t)(12u<<20))    // ablation scratch (4 MB)

// ==================================================================
// Kernel A: fused QKV projection + RoPE -> f16 buffers. (unchanged)
// ==================================================================
__global__ __launch_bounds__(64) void qkv_rope(const float* __restrict__ x,
        const float* __restrict__ Wq, const float* __restrict__ Wk,
        const float* __restrict__ Wv, char* __restrict__ wsb)
{
  const int m  = blockIdx.y;          // 0=Q 1=K 2=V
  const int t  = threadIdx.x;
  const int h  = t >> 4, dd = t & 15;
  const float* W = (m==0) ? Wq : (m==1) ? Wk : Wv;

  float4 wc[16];
  const float4* wr = (const float4*)(W + (size_t)t*EMB);
#pragma unroll
  for (int j=0;j<16;++j) wc[j] = wr[j];

  const int row0 = blockIdx.x * 8;
  const int b    = row0 >> 12;
  const int s0   = row0 & (SEQ-1);
  const int bh   = b*4 + h;

  if (m == 2){
    _Float16* Vt = (_Float16*)(wsb + VT_OFF);
    _Float16 vloc[8];
#pragma unroll
    for (int rr=0; rr<8; ++rr){
      const float4* xr = (const float4*)(x + (size_t)(row0+rr)*EMB);
      float acc = 0.f;
#pragma unroll
      for (int j=0;j<16;++j){
        const float4 xv = xr[j];
        acc = fmaf(xv.x, wc[j].x, acc);
        acc = fmaf(xv.y, wc[j].y, acc);
        acc = fmaf(xv.z, wc[j].z, acc);
        acc = fmaf(xv.w, wc[j].w, acc);
      }
      vloc[rr] = (_Float16)acc;
    }
    h8 pack = { vloc[0],vloc[1],vloc[2],vloc[3],vloc[4],vloc[5],vloc[6],vloc[7] };
    *(h8*)(Vt + ((size_t)bh*HD + dd)*SEQ + s0) = pack;
  } else {
    __shared__ float sn_l[8][8], cs_l[8][8];
    {
      const int si = t >> 3, fi = t & 7;
      const float invf = exp2f(-(float)fi * 1.6609640474436813f);
      const float ang  = (float)(s0 + si) * invf;
      float sv, cv; sincosf(ang, &sv, &cv);
      sn_l[si][fi] = sv; cs_l[si][fi] = cv;
    }
    __syncthreads();

    const float QSCALE = 0.25f * 1.44269504088896341f;
    _Float16* Qh = (_Float16*)(wsb + QH_OFF);
    _Float16* Kh = (_Float16*)(wsb + KH_OFF);
    const int fi = dd >> 1;

#pragma unroll 2
    for (int rr=0; rr<8; ++rr){
      const int s = s0 + rr;
      const float4* xr = (const float4*)(x + (size_t)(row0+rr)*EMB);
      float acc = 0.f;
#pragma unroll
      for (int j=0;j<16;++j){
        const float4 xv = xr[j];
        acc = fmaf(xv.x, wc[j].x, acc);
        acc = fmaf(xv.y, wc[j].y, acc);
        acc = fmaf(xv.z, wc[j].z, acc);
        acc = fmaf(xv.w, wc[j].w, acc);
      }
      float val = acc;
      const float part = __shfl_xor(val, 1);
      const float sn = sn_l[rr][fi], cs = cs_l[rr][fi];
      if ((dd & 1) == 0) val = val*cs - part*sn;
      else               val = part*sn + val*cs;
      if (m == 0) Qh[((size_t)bh*SEQ + s)*HD + dd] = (_Float16)(val * QSCALE);
      else        Kh[((size_t)bh*SEQ + s)*HD + dd] = (_Float16)val;
    }
  }
}

// ==================================================================
// Kernel B family: ablation variants of the flash-attention core.
// MODE 0: full kernel (real output)
// MODE 1: loads only (asm sink per chunk = real per-chunk wait)
// MODE 2: compute only (one chunk's KV, "+v" asm defeats LICM)
// MODE 3: loads + QK + exp2/cvt + la (PV o-chain removed)
// ==================================================================
struct KV { half4 k0,k1,k2,k3, v0,v1,v2,v3; };

__device__ __forceinline__ void loadKV(const _Float16* __restrict__ Kh,
                                       const _Float16* __restrict__ Vt,
                                       int ch, int lm, int kb4, KV& R)
{
  const _Float16* kp = Kh + ((size_t)(ch*64 + lm))*HD + kb4;
  R.k0 = *(const half4*)(kp +  0*HD);
  R.k1 = *(const half4*)(kp + 16*HD);
  R.k2 = *(const half4*)(kp + 32*HD);
  R.k3 = *(const half4*)(kp + 48*HD);
  const _Float16* vp = Vt + (size_t)lm*SEQ + ch*64 + kb4;
  R.v0 = *(const half4*)(vp +  0);
  R.v1 = *(const half4*)(vp + 16);
  R.v2 = *(const half4*)(vp + 32);
  R.v3 = *(const half4*)(vp + 48);
}

template<int MODE, bool MASK>
__device__ __forceinline__ void stepT(const KV& R, const half4& qf,
                                      f32x4& o, f32x4& la, int qrel, int kb4)
{
  const f32x4 C = {-FM, -FM, -FM, -FM};
  f32x4 s0 = __builtin_amdgcn_mfma_f32_16x16x16f16(R.k0, qf, C, 0, 0, 0);
  f32x4 s1 = __builtin_amdgcn_mfma_f32_16x16x16f16(R.k1, qf, C, 0, 0, 0);
  f32x4 s2 = __builtin_amdgcn_mfma_f32_16x16x16f16(R.k2, qf, C, 0, 0, 0);
  f32x4 s3 = __builtin_amdgcn_mfma_f32_16x16x16f16(R.k3, qf, C, 0, 0, 0);

  if (MASK){
#pragma unroll
    for (int r=0;r<4;++r){
      if ( 0 + kb4 + r > qrel) s0[r] = -1e30f;
      if (16 + kb4 + r > qrel) s1[r] = -1e30f;
      if (32 + kb4 + r > qrel) s2[r] = -1e30f;
      if (48 + kb4 + r > qrel) s3[r] = -1e30f;
    }
  }

  half4 hA, hB, hC, hD;
  {
    pk2 a0 = __builtin_amdgcn_cvt_pkrtz(exp2f(s0[0]), exp2f(s0[1]));
    pk2 a1 = __builtin_amdgcn_cvt_pkrtz(exp2f(s0[2]), exp2f(s0[3]));
    hA[0]=(_Float16)a0[0]; hA[1]=(_Float16)a0[1]; hA[2]=(_Float16)a1[0]; hA[3]=(_Float16)a1[1];
    pk2 b0 = __builtin_amdgcn_cvt_pkrtz(exp2f(s1[0]), exp2f(s1[1]));
    pk2 b1 = __builtin_amdgcn_cvt_pkrtz(exp2f(s1[2]), exp2f(s1[3]));
    hB[0]=(_Float16)b0[0]; hB[1]=(_Float16)b0[1]; hB[2]=(_Float16)b1[0]; hB[3]=(_Float16)b1[1];
    pk2 c0 = __builtin_amdgcn_cvt_pkrtz(exp2f(s2[0]), exp2f(s2[1]));
    pk2 c1 = __builtin_amdgcn_cvt_pkrtz(exp2f(s2[2]), exp2f(s2[3]));
    hC[0]=(_Float16)c0[0]; hC[1]=(_Float16)c0[1]; hC[2]=(_Float16)c1[0]; hC[3]=(_Float16)c1[1];
    pk2 d0 = __builtin_amdgcn_cvt_pkrtz(exp2f(s3[0]), exp2f(s3[1]));
    pk2 d1 = __builtin_amdgcn_cvt_pkrtz(exp2f(s3[2]), exp2f(s3[3]));
    hD[0]=(_Float16)d0[0]; hD[1]=(_Float16)d0[1]; hD[2]=(_Float16)d1[0]; hD[3]=(_Float16)d1[1];
  }

  if (MODE != 3){
    o = __builtin_amdgcn_mfma_f32_16x16x16f16(hA, R.v0, o, 0, 0, 0);
    o = __builtin_amdgcn_mfma_f32_16x16x16f16(hB, R.v1, o, 0, 0, 0);
    o = __builtin_amdgcn_mfma_f32_16x16x16f16(hC, R.v2, o, 0, 0, 0);
    o = __builtin_amdgcn_mfma_f32_16x16x16f16(hD, R.v3, o, 0, 0, 0);
  }

  const half4 hS = (hA + hB) + (hC + hD);
  const half4 ones = {(_Float16)1.f, (_Float16)1.f, (_Float16)1.f, (_Float16)1.f};
  la = __builtin_amdgcn_mfma_f32_16x16x16f16(hS, ones, la, 0, 0, 0);
}

template<int MODE>
__global__ __launch_bounds__(64) void attn_t(const char* __restrict__ wsb,
                                             float* __restrict__ outp)
{
  const int id   = blockIdx.x;
  const int slot = id >> 3;
  const int bh   = (id & 7)*2 + (slot & 1);
  const int qi   = 255 - (slot >> 1);
  const int l    = threadIdx.x;
  const int lm   = l & 15;
  const int kb4  = (l >> 4) * 4;

  const _Float16* __restrict__ Qh = (const _Float16*)(wsb + QH_OFF) + (size_t)bh*SEQ*HD;
  const _Float16* __restrict__ Kh = (const _Float16*)(wsb + KH_OFF) + (size_t)bh*SEQ*HD;
  const _Float16* __restrict__ Vt = (const _Float16*)(wsb + VT_OFF) + (size_t)bh*HD*SEQ;

  const int U    = qi >> 2;
  const int qrel = (qi & 3)*16 + lm;

  if (MODE == 1){
    // loads only: issue 8 loads/chunk, sink forces the per-chunk wait
    KV R;
    for (int ch=0; ch<=U; ++ch){
      loadKV(Kh, Vt, ch, lm, kb4, R);
      asm volatile("" :: "v"(R.k0),"v"(R.k1),"v"(R.k2),"v"(R.k3),
                         "v"(R.v0),"v"(R.v1),"v"(R.v2),"v"(R.v3));
    }
    return;
  }

  const half4 qf = *(const half4*)(Qh + ((size_t)(qi*16 + lm))*HD + kb4);
  f32x4 o  = {0.f,0.f,0.f,0.f};
  f32x4 la = {0.f,0.f,0.f,0.f};

  if (MODE == 2){
    // compute only: one chunk's KV reused; "+v" asm makes R opaque per iter
    KV R;
    loadKV(Kh, Vt, 0, lm, kb4, R);
    for (int ch=0; ch<U; ++ch){
      asm volatile("" : "+v"(R.k0),"+v"(R.k1),"+v"(R.k2),"+v"(R.k3),
                        "+v"(R.v0),"+v"(R.v1),"+v"(R.v2),"+v"(R.v3));
      stepT<2,false>(R, qf, o, la, qrel, kb4);
    }
    stepT<2,true>(R, qf, o, la, qrel, kb4);
  } else {  // MODE 0 or 3
    KV R;
    for (int ch=0; ch<U; ++ch){
      loadKV(Kh, Vt, ch, lm, kb4, R);
      stepT<MODE,false>(R, qf, o, la, qrel, kb4);
    }
    loadKV(Kh, Vt, U, lm, kb4, R);
    stepT<MODE,true>(R, qf, o, la, qrel, kb4);
  }

  const int b = bh >> 2, h = bh & 3;
#pragma unroll
  for (int r=0;r<4;++r){
    const int qg = qi*16 + kb4 + r;
    const float v = (MODE == 0) ? (o[r] / la[r]) : (o[r] + la[r]);
    outp[((size_t)b*SEQ + qg)*EMB + h*HD + lm] = v;
  }
}

// ==================================================================
// Kernel C: output projection  out = att @ Wo.T  (fp32) (unchanged)
// ==================================================================
__global__ __launch_bounds__(64) void oproj(const float* __restrict__ att,
        const float* __restrict__ Wo, float* __restrict__ out)
{
  const int t = threadIdx.x;
  float4 wc[16];
  const float4* wr = (const float4*)(Wo + (size_t)t*EMB);
#pragma unroll
  for (int j=0;j<16;++j) wc[j] = wr[j];

  const int row0 = blockIdx.x * 8;
#pragma unroll 2
  for (int rr=0; rr<8; ++rr){
    const int row = row0 + rr;
    const float4* ar = (const float4*)(att + (size_t)row*EMB);
    float acc = 0.f;
#pragma unroll
    for (int j=0;j<16;++j){
      const float4 av = ar[j];
      acc = fmaf(av.x, wc[j].x, acc);
      acc = fmaf(av.y, wc[j].y, acc);
      acc = fmaf(av.z, wc[j].z, acc);
      acc = fmaf(av.w, wc[j].w, acc);
    }
    out[(size_t)row*EMB + t] = acc;
  }
}

extern "C" void kernel_launch(void* const* d_in, const int* in_sizes, int n_in,
                              void* d_out, int out_size, void* d_ws, size_t ws_size,
                              hipStream_t stream)
{
  const float* x  = (const float*)d_in[0];
  const float* Wq = (const float*)d_in[1];
  const float* Wk = (const float*)d_in[2];
  const float* Wv = (const float*)d_in[3];
  const float* Wo = (const float*)d_in[4];
  char*  wsb = (char*)d_ws;
  float* att = (float*)(wsb + ATT_OFF);
  float* scr = (float*)(wsb + SCR_OFF);
  float* out = (float*)d_out;

  qkv_rope <<<dim3(2048,3,1), 64, 0, stream>>>(x, Wq, Wk, Wv, wsb);
  attn_t<1><<<dim3(4096,1,1), 64, 0, stream>>>(wsb, scr);   // loads-only probe
  attn_t<2><<<dim3(4096,1,1), 64, 0, stream>>>(wsb, scr);   // compute-only probe
  attn_t<3><<<dim3(4096,1,1), 64, 0, stream>>>(wsb, scr);   // no-PV probe
  attn_t<0><<<dim3(4096,1,1), 64, 0, stream>>>(wsb, att);   // real result
  oproj    <<<dim3(2048,1,1), 64, 0, stream>>>(att, Wo, out);
}

// Round 14
// 135.753 us; speedup vs baseline: 2.4235x; 2.4235x over previous
//
#include <hip/hip_runtime.h>
#include <math.h>

#define SEQ 4096
#define HD  16
#define EMB 64
#define FM  12.0f     // fixed softmax max (log2-domain)

typedef _Float16 half4  __attribute__((ext_vector_type(4)));
typedef __fp16   pk2    __attribute__((ext_vector_type(2)));   // cvt_pkrtz result type
typedef _Float16 h8     __attribute__((ext_vector_type(8)));
typedef float    f32x4  __attribute__((ext_vector_type(4)));

// ---- ws byte layout ----
#define QH_OFF  ((size_t)0)            // f16 [16][4096][16], Q pre-scaled
#define KH_OFF  ((size_t)(2u<<20))     // f16 [16][4096][16]
#define VT_OFF  ((size_t)(4u<<20))     // f16 [16][16][4096]  (V transposed)
#define ATT_OFF ((size_t)(8u<<20))     // f32 [4][4096][64]

// ==================================================================
// Kernel A: fused QKV projection + RoPE -> f16 buffers.
// x rows staged in LDS (coalesced). FIX: stage loop is 2 iterations
// (8 rows x 16 float4 = 128 elems / 64 threads), was 8 -> LDS+global OOB.
// ==================================================================
__global__ __launch_bounds__(64) void qkv_rope(const float* __restrict__ x,
        const float* __restrict__ Wq, const float* __restrict__ Wk,
        const float* __restrict__ Wv, char* __restrict__ wsb)
{
  const int m  = blockIdx.y;          // 0=Q 1=K 2=V
  const int t  = threadIdx.x;
  const int h  = t >> 4, dd = t & 15;
  const float* W = (m==0) ? Wq : (m==1) ? Wk : Wv;

  float4 wc[16];
  const float4* wr = (const float4*)(W + (size_t)t*EMB);
#pragma unroll
  for (int j=0;j<16;++j) wc[j] = wr[j];

  const int row0 = blockIdx.x * 8;
  const int b    = row0 >> 12;
  const int s0   = row0 & (SEQ-1);
  const int bh   = b*4 + h;

  // stage the block's 8 x-rows: 128 float4 total, 2 per thread
  __shared__ float4 xs[8][16];
  __shared__ float sn_l[8][8], cs_l[8][8];
  {
    const float4* x4 = (const float4*)x;
#pragma unroll
    for (int j2=0; j2<2; ++j2){
      const int f = j2*64 + t;                  // 0..127
      xs[f>>4][f&15] = x4[(size_t)row0*16 + f];
    }
    if (m < 2){
      const int si = t >> 3, fi = t & 7;
      const float invf = exp2f(-(float)fi * 1.6609640474436813f);
      const float ang  = (float)(s0 + si) * invf;
      float sv, cv; sincosf(ang, &sv, &cv);
      sn_l[si][fi] = sv; cs_l[si][fi] = cv;
    }
  }
  __syncthreads();

  if (m == 2){
    _Float16* Vt = (_Float16*)(wsb + VT_OFF);
    _Float16 vloc[8];
#pragma unroll
    for (int rr=0; rr<8; ++rr){
      float acc = 0.f;
#pragma unroll
      for (int j=0;j<16;++j){
        const float4 xv = xs[rr][j];            // LDS broadcast
        acc = fmaf(xv.x, wc[j].x, acc);
        acc = fmaf(xv.y, wc[j].y, acc);
        acc = fmaf(xv.z, wc[j].z, acc);
        acc = fmaf(xv.w, wc[j].w, acc);
      }
      vloc[rr] = (_Float16)acc;
    }
    h8 pack = { vloc[0],vloc[1],vloc[2],vloc[3],vloc[4],vloc[5],vloc[6],vloc[7] };
    *(h8*)(Vt + ((size_t)bh*HD + dd)*SEQ + s0) = pack;
  } else {
    const float QSCALE = 0.25f * 1.44269504088896341f;
    _Float16* Qh = (_Float16*)(wsb + QH_OFF);
    _Float16* Kh = (_Float16*)(wsb + KH_OFF);
    const int fi = dd >> 1;

#pragma unroll 2
    for (int rr=0; rr<8; ++rr){
      const int s = s0 + rr;
      float acc = 0.f;
#pragma unroll
      for (int j=0;j<16;++j){
        const float4 xv = xs[rr][j];            // LDS broadcast
        acc = fmaf(xv.x, wc[j].x, acc);
        acc = fmaf(xv.y, wc[j].y, acc);
        acc = fmaf(xv.z, wc[j].z, acc);
        acc = fmaf(xv.w, wc[j].w, acc);
      }
      float val = acc;
      const float part = __shfl_xor(val, 1);
      const float sn = sn_l[rr][fi], cs = cs_l[rr][fi];
      if ((dd & 1) == 0) val = val*cs - part*sn;   // rot_even
      else               val = part*sn + val*cs;   // rot_odd
      if (m == 0) Qh[((size_t)bh*SEQ + s)*HD + dd] = (_Float16)(val * QSCALE);
      else        Kh[((size_t)bh*SEQ + s)*HD + dd] = (_Float16)val;
    }
  }
}

// ==================================================================
// Kernel B: causal flash attention, f16 MFMA, fixed-max softmax.
// 4 waves/block share each K/V chunk via LDS (unchanged from r12).
// grid 1024 x 256; XCD swizzle (2 bh/XCD), longest t first.
// ==================================================================
struct KV { half4 k0,k1,k2,k3, v0,v1,v2,v3; };

template<bool MASK>
__device__ __forceinline__ void step(const KV& R, const half4& qf,
                                     f32x4& o, f32x4& la, int qrel, int kb4)
{
  const f32x4 C = {-FM, -FM, -FM, -FM};       // -max folded into the matmul
  f32x4 s0 = __builtin_amdgcn_mfma_f32_16x16x16f16(R.k0, qf, C, 0, 0, 0);
  f32x4 s1 = __builtin_amdgcn_mfma_f32_16x16x16f16(R.k1, qf, C, 0, 0, 0);
  f32x4 s2 = __builtin_amdgcn_mfma_f32_16x16x16f16(R.k2, qf, C, 0, 0, 0);
  f32x4 s3 = __builtin_amdgcn_mfma_f32_16x16x16f16(R.k3, qf, C, 0, 0, 0);

  if (MASK){
#pragma unroll
    for (int r=0;r<4;++r){
      if ( 0 + kb4 + r > qrel) s0[r] = -1e30f;
      if (16 + kb4 + r > qrel) s1[r] = -1e30f;
      if (32 + kb4 + r > qrel) s2[r] = -1e30f;
      if (48 + kb4 + r > qrel) s3[r] = -1e30f;
    }
  }

  half4 hA, hB, hC, hD;
  {
    pk2 a0 = __builtin_amdgcn_cvt_pkrtz(exp2f(s0[0]), exp2f(s0[1]));
    pk2 a1 = __builtin_amdgcn_cvt_pkrtz(exp2f(s0[2]), exp2f(s0[3]));
    hA[0]=(_Float16)a0[0]; hA[1]=(_Float16)a0[1]; hA[2]=(_Float16)a1[0]; hA[3]=(_Float16)a1[1];
    pk2 b0 = __builtin_amdgcn_cvt_pkrtz(exp2f(s1[0]), exp2f(s1[1]));
    pk2 b1 = __builtin_amdgcn_cvt_pkrtz(exp2f(s1[2]), exp2f(s1[3]));
    hB[0]=(_Float16)b0[0]; hB[1]=(_Float16)b0[1]; hB[2]=(_Float16)b1[0]; hB[3]=(_Float16)b1[1];
    pk2 c0 = __builtin_amdgcn_cvt_pkrtz(exp2f(s2[0]), exp2f(s2[1]));
    pk2 c1 = __builtin_amdgcn_cvt_pkrtz(exp2f(s2[2]), exp2f(s2[3]));
    hC[0]=(_Float16)c0[0]; hC[1]=(_Float16)c0[1]; hC[2]=(_Float16)c1[0]; hC[3]=(_Float16)c1[1];
    pk2 d0 = __builtin_amdgcn_cvt_pkrtz(exp2f(s3[0]), exp2f(s3[1]));
    pk2 d1 = __builtin_amdgcn_cvt_pkrtz(exp2f(s3[2]), exp2f(s3[3]));
    hD[0]=(_Float16)d0[0]; hD[1]=(_Float16)d0[1]; hD[2]=(_Float16)d1[0]; hD[3]=(_Float16)d1[1];
  }

  o = __builtin_amdgcn_mfma_f32_16x16x16f16(hA, R.v0, o, 0, 0, 0);
  o = __builtin_amdgcn_mfma_f32_16x16x16f16(hB, R.v1, o, 0, 0, 0);
  o = __builtin_amdgcn_mfma_f32_16x16x16f16(hC, R.v2, o, 0, 0, 0);
  o = __builtin_amdgcn_mfma_f32_16x16x16f16(hD, R.v3, o, 0, 0, 0);

  // l via ones-MFMA: same fragment layout as o -> per-lane divide epilogue
  const half4 hS = (hA + hB) + (hC + hD);
  const half4 ones = {(_Float16)1.f, (_Float16)1.f, (_Float16)1.f, (_Float16)1.f};
  la = __builtin_amdgcn_mfma_f32_16x16x16f16(hS, ones, la, 0, 0, 0);
}

__global__ __launch_bounds__(256) void attn(const char* __restrict__ wsb,
                                            float* __restrict__ att)
{
  const int id   = blockIdx.x;            // 0..1023
  const int slot = id >> 3;               // 0..127 per XCD
  const int bh   = (id & 7)*2 + (slot & 1);
  const int t    = 63 - (slot >> 1);      // q-group, longest first
  const int tid  = threadIdx.x;
  const int w    = tid >> 6;              // wave -> q-tile qi = 4t+w
  const int l    = tid & 63;
  const int lm   = l & 15;
  const int kb4  = (l >> 4) * 4;
  const int qi   = 4*t + w;
  const int U    = t;                     // uniform chunk count for all waves
  const int qrel = w*16 + lm;             // q position within diagonal chunk

  const _Float16* __restrict__ Qh = (const _Float16*)(wsb + QH_OFF) + (size_t)bh*SEQ*HD;
  const _Float16* __restrict__ Kh = (const _Float16*)(wsb + KH_OFF) + (size_t)bh*SEQ*HD;
  const _Float16* __restrict__ Vt = (const _Float16*)(wsb + VT_OFF) + (size_t)bh*HD*SEQ;

  // padded rows: K stride 48B, V stride 144B -> <=4-way bank aliasing
  __shared__ _Float16 Klds[2][64][24];
  __shared__ _Float16 Vlds[2][16][72];

  const half4 qf = *(const half4*)(Qh + ((size_t)(qi*16 + lm))*HD + kb4);
  f32x4 o  = {0.f,0.f,0.f,0.f};
  f32x4 la = {0.f,0.f,0.f,0.f};

  // per-thread stage indices: K key=tid>>2, d=(tid&3)*4; V d=tid>>4, key=(tid&15)*4
  const int skey = tid >> 2, sd = (tid & 3) * 4;
  const int vd   = tid >> 4, vk = (tid & 15) * 4;

  { // prologue: stage chunk 0 into buf 0
    half4 kreg = *(const half4*)(Kh + ((size_t)skey)*HD + sd);
    half4 vreg = *(const half4*)(Vt + (size_t)vd*SEQ + vk);
    *(half4*)&Klds[0][skey][sd] = kreg;
    *(half4*)&Vlds[0][vd][vk]   = vreg;
  }
  __syncthreads();

  for (int ch = 0; ch < U; ++ch){
    const int cur = ch & 1;
    // issue next chunk's coalesced loads early (latency hides under compute)
    half4 kreg = *(const half4*)(Kh + ((size_t)((ch+1)*64 + skey))*HD + sd);
    half4 vreg = *(const half4*)(Vt + (size_t)vd*SEQ + (ch+1)*64 + vk);

    KV R;
    R.k0 = *(const half4*)&Klds[cur][ 0+lm][kb4];
    R.k1 = *(const half4*)&Klds[cur][16+lm][kb4];
    R.k2 = *(const half4*)&Klds[cur][32+lm][kb4];
    R.k3 = *(const half4*)&Klds[cur][48+lm][kb4];
    R.v0 = *(const half4*)&Vlds[cur][lm][ 0+kb4];
    R.v1 = *(const half4*)&Vlds[cur][lm][16+kb4];
    R.v2 = *(const half4*)&Vlds[cur][lm][32+kb4];
    R.v3 = *(const half4*)&Vlds[cur][lm][48+kb4];
    step<false>(R, qf, o, la, qrel, kb4);

    // write-late into the other buffer (prev compute of buf^1 is behind
    // the previous iteration's barrier)
    *(half4*)&Klds[cur^1][skey][sd] = kreg;
    *(half4*)&Vlds[cur^1][vd][vk]   = vreg;
    __syncthreads();
  }

  { // diagonal chunk U (masked), no prefetch
    const int cur = U & 1;
    KV R;
    R.k0 = *(const half4*)&Klds[cur][ 0+lm][kb4];
    R.k1 = *(const half4*)&Klds[cur][16+lm][kb4];
    R.k2 = *(const half4*)&Klds[cur][32+lm][kb4];
    R.k3 = *(const half4*)&Klds[cur][48+lm][kb4];
    R.v0 = *(const half4*)&Vlds[cur][lm][ 0+kb4];
    R.v1 = *(const half4*)&Vlds[cur][lm][16+kb4];
    R.v2 = *(const half4*)&Vlds[cur][lm][32+kb4];
    R.v3 = *(const half4*)&Vlds[cur][lm][48+kb4];
    step<true>(R, qf, o, la, qrel, kb4);
  }

  const int b = bh >> 2, h = bh & 3;
#pragma unroll
  for (int r=0;r<4;++r){
    const int qg = qi*16 + kb4 + r;
    att[((size_t)b*SEQ + qg)*EMB + h*HD + lm] = o[r] / la[r];
  }
}

// ==================================================================
// Kernel C: output projection  out = att @ Wo.T  (fp32)
// att rows staged in LDS; FIX: 2-iteration stage loop (was 8, OOB).
// ==================================================================
__global__ __launch_bounds__(64) void oproj(const float* __restrict__ att,
        const float* __restrict__ Wo, float* __restrict__ out)
{
  const int t = threadIdx.x;
  float4 wc[16];
  const float4* wr = (const float4*)(Wo + (size_t)t*EMB);
#pragma unroll
  for (int j=0;j<16;++j) wc[j] = wr[j];

  const int row0 = blockIdx.x * 8;
  __shared__ float4 xs[8][16];
  {
    const float4* a4 = (const float4*)att;
#pragma unroll
    for (int j2=0; j2<2; ++j2){
      const int f = j2*64 + t;                  // 0..127
      xs[f>>4][f&15] = a4[(size_t)row0*16 + f];
    }
  }
  __syncthreads();

#pragma unroll 2
  for (int rr=0; rr<8; ++rr){
    float acc = 0.f;
#pragma unroll
    for (int j=0;j<16;++j){
      const float4 av = xs[rr][j];              // LDS broadcast
      acc = fmaf(av.x, wc[j].x, acc);
      acc = fmaf(av.y, wc[j].y, acc);
      acc = fmaf(av.z, wc[j].z, acc);
      acc = fmaf(av.w, wc[j].w, acc);
    }
    out[(size_t)(row0+rr)*EMB + t] = acc;
  }
}

extern "C" void kernel_launch(void* const* d_in, const int* in_sizes, int n_in,
                              void* d_out, int out_size, void* d_ws, size_t ws_size,
                              hipStream_t stream)
{
  const float* x  = (const float*)d_in[0];
  const float* Wq = (const float*)d_in[1];
  const float* Wk = (const float*)d_in[2];
  const float* Wv = (const float*)d_in[3];
  const float* Wo = (const float*)d_in[4];
  char*  wsb = (char*)d_ws;
  float* att = (float*)(wsb + ATT_OFF);
  float* out = (float*)d_out;

  qkv_rope<<<dim3(2048,3,1),  64, 0, stream>>>(x, Wq, Wk, Wv, wsb);
  attn    <<<dim3(1024,1,1), 256, 0, stream>>>(wsb, att);
  oproj   <<<dim3(2048,1,1),  64, 0, stream>>>(att, Wo, out);
}